// Round 5
// baseline (1024.186 us; speedup 1.0000x reference)
//
#include <hip/hip_runtime.h>
#include <hip/hip_bf16.h>

// Problem constants (B=1)
#define N_TOK 8192
#define DIM   1024
#define NEXP  8
#define FF    4096
#define CAP   2560            // int(8192*2*1.25/8)
#define NASSIGN (N_TOK * 2)   // K=2, slot-major: j = s*N + t

typedef __bf16 bf16;
typedef __bf16 bf16x8 __attribute__((ext_vector_type(8)));
typedef __bf16 bf16x4v __attribute__((ext_vector_type(4)));
typedef float  f32x4  __attribute__((ext_vector_type(4)));

// async global->LDS DMA, 16B per lane. LDS dest = wave-uniform base + lane*16.
__device__ __forceinline__ void gl2lds16(const bf16* g, bf16* l) {
    __builtin_amdgcn_global_load_lds(
        (const __attribute__((address_space(1))) unsigned int*)g,
        (__attribute__((address_space(3))) unsigned int*)l,
        16, 0, 0);
}

// ---------------------------------------------------------------------------
// Shared 256x256x64 8-phase GEMM core (m201-style schedule).
// 512 thr = 8 waves (2M x 4N), per-wave 128x64 out = 8x4 frags of 16x16x32.
// LDS: dbuf x (A 256x64 + B 256x64) bf16 = 128 KB, 1 block/CU.
// Per K-tile: vmcnt(8) [counted; 0 only on the last tile] -> barrier ->
// 4 phases {ds_read cluster -> barrier -> lgkmcnt(0)+sched_barrier ->
// setprio(1) 16 MFMA setprio(0) -> barrier} -> STAGE(kt+2).
// Phase p: mh=p>>1 (A frags m=mh*4..+4, read at p0/p2, held 2 phases),
//          nh=p&1  (B frags n=nh*2..+2, read each phase).
// Swizzle involution: linear DMA dest; global source chunk = (lane&7)^(lane>>3);
// ds_read phys chunk = (kk*4+c16)^(row&7). Staging: wave w, group g stages
// rows g*64 + w*8 + (lane>>3) -> full 256-row coverage for A and B.
// 8 gl2lds/thread/tile -> vmcnt(8) leaves exactly the next tile in flight.
// ---------------------------------------------------------------------------
template <int NT>
__device__ __forceinline__ void gemm256_core(
    const bf16* __restrict__ gA, size_t astep,   // per-group global row stride (elems)
    const bf16* __restrict__ gB, size_t bstep,
    bf16* As, bf16* Bs, f32x4 acc[8][4], int wave, int lane)
{
    const int wm = wave >> 2, wn = wave & 3;
    const int r16 = lane & 15, c16 = lane >> 4;

    auto STAGE = [&](int kt) {
        const int b = kt & 1;
        const bf16* a  = gA + kt * 64;
        const bf16* bb = gB + kt * 64;
#pragma unroll
        for (int g = 0; g < 4; ++g)
            gl2lds16(a + (size_t)g * astep, &As[b * (256 * 64) + (g * 64 + wave * 8) * 64]);
#pragma unroll
        for (int g = 0; g < 4; ++g)
            gl2lds16(bb + (size_t)g * bstep, &Bs[b * (256 * 64) + (g * 64 + wave * 8) * 64]);
    };

    STAGE(0);
    STAGE(1);

    bf16x8 af[4][2], bfr[2][2];

    for (int kt = 0; kt < NT; ++kt) {
        if (kt < NT - 1) asm volatile("s_waitcnt vmcnt(8)" ::: "memory");
        else             asm volatile("s_waitcnt vmcnt(0)" ::: "memory");
        __builtin_amdgcn_sched_barrier(0);
        __builtin_amdgcn_s_barrier();
        __builtin_amdgcn_sched_barrier(0);
        const bf16* Asb = &As[(kt & 1) * (256 * 64)];
        const bf16* Bsb = &Bs[(kt & 1) * (256 * 64)];

#define DS_A(mh)                                                          \
        _Pragma("unroll")                                                 \
        for (int m = 0; m < 4; ++m) {                                     \
            _Pragma("unroll")                                             \
            for (int kk = 0; kk < 2; ++kk) {                              \
                int row = wm * 128 + (mh) * 64 + m * 16 + r16;            \
                int phys = (kk * 4 + c16) ^ (row & 7);                    \
                af[m][kk] = *(const bf16x8*)&Asb[row * 64 + phys * 8];    \
            } }
#define DS_B(nh)                                                          \
        _Pragma("unroll")                                                 \
        for (int n = 0; n < 2; ++n) {                                     \
            _Pragma("unroll")                                             \
            for (int kk = 0; kk < 2; ++kk) {                              \
                int row = wn * 64 + ((nh) * 2 + n) * 16 + r16;            \
                int phys = (kk * 4 + c16) ^ (row & 7);                    \
                bfr[n][kk] = *(const bf16x8*)&Bsb[row * 64 + phys * 8];   \
            } }
#define PH_IN                                                             \
        __builtin_amdgcn_sched_barrier(0);                                \
        __builtin_amdgcn_s_barrier();                                     \
        asm volatile("s_waitcnt lgkmcnt(0)" ::: "memory");                \
        __builtin_amdgcn_sched_barrier(0);
#define PH_MFMA(mh, nh)                                                   \
        __builtin_amdgcn_s_setprio(1);                                    \
        _Pragma("unroll")                                                 \
        for (int m = 0; m < 4; ++m)                                       \
            _Pragma("unroll")                                             \
            for (int n = 0; n < 2; ++n)                                   \
                _Pragma("unroll")                                         \
                for (int kk = 0; kk < 2; ++kk)                            \
                    acc[(mh) * 4 + m][(nh) * 2 + n] =                     \
                        __builtin_amdgcn_mfma_f32_16x16x32_bf16(          \
                            af[m][kk], bfr[n][kk],                        \
                            acc[(mh) * 4 + m][(nh) * 2 + n], 0, 0, 0);    \
        __builtin_amdgcn_s_setprio(0);
#define PH_OUT                                                            \
        __builtin_amdgcn_sched_barrier(0);                                \
        __builtin_amdgcn_s_barrier();                                     \
        __builtin_amdgcn_sched_barrier(0);

        DS_A(0) DS_B(0) PH_IN PH_MFMA(0, 0) PH_OUT
        DS_B(1)         PH_IN PH_MFMA(0, 1) PH_OUT
        DS_A(1) DS_B(0) PH_IN PH_MFMA(1, 0) PH_OUT
        DS_B(1)         PH_IN PH_MFMA(1, 1) PH_OUT

#undef DS_A
#undef DS_B
#undef PH_IN
#undef PH_MFMA
#undef PH_OUT

        if (kt + 2 < NT) STAGE(kt + 2);
    }
}

// ---------------------------------------------------------------------------
// fp32 -> bf16 weight conversion
// ---------------------------------------------------------------------------
__global__ __launch_bounds__(256) void cvt_bf16_kernel(const float* __restrict__ in,
                                                       bf16* __restrict__ out, int n) {
    int stride = gridDim.x * blockDim.x * 8;
    for (int i = (blockIdx.x * blockDim.x + threadIdx.x) * 8; i < n; i += stride) {
        float4 a = *(const float4*)(in + i);
        float4 b = *(const float4*)(in + i + 4);
        bf16x8 o;
        o[0] = (bf16)a.x; o[1] = (bf16)a.y; o[2] = (bf16)a.z; o[3] = (bf16)a.w;
        o[4] = (bf16)b.x; o[5] = (bf16)b.y; o[6] = (bf16)b.z; o[7] = (bf16)b.w;
        *(bf16x8*)(out + i) = o;
    }
}

// ---------------------------------------------------------------------------
// Router: logits in fp64 (top-k selection robustness), softmax, top-2.
// ---------------------------------------------------------------------------
__global__ __launch_bounds__(256) void router_kernel(const float* __restrict__ x,
                                                     const float* __restrict__ Wr,
                                                     float* __restrict__ probs,
                                                     int* __restrict__ topi,
                                                     float* __restrict__ topw) {
    int wave = threadIdx.x >> 6;
    int lane = threadIdx.x & 63;
    int t = blockIdx.x * 4 + wave;
    const float* xr = x + (size_t)t * DIM;

    double acc[NEXP];
#pragma unroll
    for (int e = 0; e < NEXP; ++e) acc[e] = 0.0;
    for (int i = lane; i < DIM; i += 64) {
        double xv = (double)xr[i];
#pragma unroll
        for (int e = 0; e < NEXP; ++e) acc[e] += xv * (double)Wr[e * DIM + i];
    }
#pragma unroll
    for (int e = 0; e < NEXP; ++e) {
        double v = acc[e];
        for (int off = 32; off > 0; off >>= 1) v += __shfl_down(v, off, 64);
        acc[e] = v;  // valid on lane 0
    }
    if (lane == 0) {
        double mx = acc[0];
        for (int e = 1; e < NEXP; ++e) if (acc[e] > mx) mx = acc[e];
        double p[NEXP], s = 0.0;
        for (int e = 0; e < NEXP; ++e) { p[e] = exp(acc[e] - mx); s += p[e]; }
        float pf[NEXP];
        for (int e = 0; e < NEXP; ++e) { pf[e] = (float)(p[e] / s); probs[t * NEXP + e] = pf[e]; }
        int e1 = 0;
        for (int e = 1; e < NEXP; ++e) if (acc[e] > acc[e1]) e1 = e;
        int e2 = -1;
        for (int e = 0; e < NEXP; ++e) {
            if (e == e1) continue;
            if (e2 < 0 || acc[e] > acc[e2]) e2 = e;
        }
        float w1 = pf[e1], w2 = pf[e2];
        float inv = 1.0f / (w1 + w2 + 1e-9f);
        topi[t * 2 + 0] = e1; topi[t * 2 + 1] = e2;
        topw[t * 2 + 0] = w1 * inv; topw[t * 2 + 1] = w2 * inv;
    }
}

// ---------------------------------------------------------------------------
// Rank/capacity in exact slot-major reference order. One wave per expert.
// ---------------------------------------------------------------------------
__global__ __launch_bounds__(64) void rank_kernel(const int* __restrict__ topi,
                                                  int* __restrict__ dest,
                                                  int* __restrict__ accf,
                                                  int* __restrict__ counts) {
    int e = blockIdx.x;
    int lane = threadIdx.x;
    const int per = NASSIGN / 64;  // 256
    int base = lane * per;
    int cnt = 0;
    for (int i = 0; i < per; ++i) {
        int j = base + i;
        int t = j & (N_TOK - 1), s = j >> 13;
        if (topi[t * 2 + s] == e) cnt++;
    }
    int sum = cnt;
    for (int off = 1; off < 64; off <<= 1) {
        int v = __shfl_up(sum, off, 64);
        if (lane >= off) sum += v;
    }
    int r = sum - cnt;                       // exclusive prefix
    int total = __shfl(sum, 63, 64);
    for (int i = 0; i < per; ++i) {
        int j = base + i;
        int t = j & (N_TOK - 1), s = j >> 13;
        if (topi[t * 2 + s] == e) {
            int acc = (r < CAP) ? 1 : 0;
            dest[j] = e * CAP + (acc ? r : 0);
            accf[j] = acc;
            r++;
        }
    }
    if (lane == 63) counts[e] = (total < CAP) ? total : CAP;
}

// ---------------------------------------------------------------------------
// Gather: x row -> bf16 capacity buffer row. One block per assignment.
// ---------------------------------------------------------------------------
__global__ __launch_bounds__(256) void gather_kernel(const float* __restrict__ x,
                                                     const int* __restrict__ dest,
                                                     const int* __restrict__ accf,
                                                     bf16* __restrict__ Xe) {
    int j = blockIdx.x;
    if (!accf[j]) return;
    int t = j & (N_TOK - 1);
    int d0 = threadIdx.x * 4;
    float4 v = *(const float4*)(x + (size_t)t * DIM + d0);
    union { bf16 h[4]; uint2 u; } tmp;
    tmp.h[0] = (bf16)v.x; tmp.h[1] = (bf16)v.y; tmp.h[2] = (bf16)v.z; tmp.h[3] = (bf16)v.w;
    *(uint2*)(Xe + (size_t)dest[j] * DIM + d0) = tmp.u;
}

// ---------------------------------------------------------------------------
// gateup: BM=256 tokens x BN=256 "interleaved" cols = 128 FF cols x {gate,up}.
// B tile rows r: tensor=(r>>4)&1 (0=gate,1=up), ffc = n0f + (r>>6)*32 +
// ((r>>5)&1)*16 + (r&15). Per wave: even n-frags = gate, odd = up, SAME 16
// logical cols -> silu(g)*u pairs thread-local in the epilogue.
// Staging B base (row rsub<64): affine, per-group stride 32*DIM.
// ---------------------------------------------------------------------------
__global__ __launch_bounds__(512, 2) void gateup_kernel(const bf16* __restrict__ Xe,
                                                        const bf16* __restrict__ Wg,
                                                        const bf16* __restrict__ Wu,
                                                        bf16* __restrict__ hbuf) {
    const int e = blockIdx.z;
    const int m0 = blockIdx.x * 256;
    const int n0f = blockIdx.y * 128;
    const int tid = threadIdx.x, lane = tid & 63, wave = tid >> 6;
    const int wm = wave >> 2, wn = wave & 3;
    const int r16 = lane & 15, c16 = lane >> 4;

    __shared__ bf16 As[2 * 256 * 64];
    __shared__ bf16 Bs[2 * 256 * 64];

    const int rsub = wave * 8 + (lane >> 3);            // [0,64)
    const int csw  = ((lane & 7) ^ (lane >> 3)) * 8;    // pre-swizzled chunk
    const bf16* gA = Xe + (size_t)e * CAP * DIM + (size_t)(m0 + rsub) * DIM + csw;
    const int bff = n0f + ((rsub >> 5) & 1) * 16 + (rsub & 15);
    const bf16* gB = (((rsub >> 4) & 1) ? Wu : Wg)
                   + (size_t)e * FF * DIM + (size_t)bff * DIM + csw;

    f32x4 acc[8][4] = {};
    gemm256_core<DIM / 64>(gA, (size_t)64 * DIM, gB, (size_t)32 * DIM, As, Bs, acc, wave, lane);

    bf16* hp = hbuf + (size_t)e * CAP * FF;
#pragma unroll
    for (int m = 0; m < 8; ++m)
#pragma unroll
        for (int np = 0; np < 2; ++np)
#pragma unroll
            for (int j = 0; j < 4; ++j) {
                float g = acc[m][2 * np + 0][j];
                float u = acc[m][2 * np + 1][j];
                float h = (g / (1.f + __expf(-g))) * u;
                int gr = m0 + wm * 128 + m * 16 + c16 * 4 + j;
                int gc = n0f + wn * 32 + np * 16 + r16;
                hp[(size_t)gr * FF + gc] = (bf16)h;
            }
}

// ---------------------------------------------------------------------------
// down: BM=256 x BN=256, split-K=2 (kh = blockIdx.z&1, K-half 2048 = 32
// K-tiles). Output: bf16 partial sums into eo[kh]; combine sums both halves.
// ---------------------------------------------------------------------------
__global__ __launch_bounds__(512, 2) void down_kernel(const bf16* __restrict__ hbuf,
                                                      const bf16* __restrict__ Wd,
                                                      bf16* __restrict__ eo) {
    const int e  = blockIdx.z >> 1;
    const int kh = blockIdx.z & 1;
    const int m0 = blockIdx.x * 256;
    const int n0 = blockIdx.y * 256;
    const int tid = threadIdx.x, lane = tid & 63, wave = tid >> 6;
    const int wm = wave >> 2, wn = wave & 3;
    const int r16 = lane & 15, c16 = lane >> 4;

    __shared__ bf16 As[2 * 256 * 64];
    __shared__ bf16 Bs[2 * 256 * 64];

    const int rsub = wave * 8 + (lane >> 3);
    const int csw  = ((lane & 7) ^ (lane >> 3)) * 8;
    const bf16* gA = hbuf + (size_t)e * CAP * FF + (size_t)(m0 + rsub) * FF + kh * (FF / 2) + csw;
    const bf16* gB = Wd + (size_t)e * DIM * FF + (size_t)(n0 + rsub) * FF + kh * (FF / 2) + csw;

    f32x4 acc[8][4] = {};
    gemm256_core<FF / 128>(gA, (size_t)64 * FF, gB, (size_t)64 * FF, As, Bs, acc, wave, lane);

    bf16* op = eo + (size_t)kh * NEXP * CAP * DIM + (size_t)e * CAP * DIM;
#pragma unroll
    for (int m = 0; m < 8; ++m)
#pragma unroll
        for (int n = 0; n < 4; ++n)
#pragma unroll
            for (int j = 0; j < 4; ++j) {
                int gr = m0 + wm * 128 + m * 16 + c16 * 4 + j;
                int gc = n0 + wn * 64 + n * 16 + r16;
                op[(size_t)gr * DIM + gc] = (bf16)acc[m][n][j];
            }
}

// ---------------------------------------------------------------------------
// Combine: out[t] = sum_s w_ts * acc_ts * (eo0[dest_ts] + eo1[dest_ts]).
// ---------------------------------------------------------------------------
__global__ __launch_bounds__(256) void combine_kernel(const bf16* __restrict__ eo,
                                                      const int* __restrict__ dest,
                                                      const int* __restrict__ accf,
                                                      const float* __restrict__ topw,
                                                      float* __restrict__ out) {
    int t = blockIdx.x;
    float w0 = accf[t] ? topw[t * 2 + 0] : 0.f;           // slot 0: j = t
    float w1 = accf[N_TOK + t] ? topw[t * 2 + 1] : 0.f;   // slot 1: j = N + t
    size_t off1 = (size_t)NEXP * CAP * DIM;
    const bf16* a0 = eo + (size_t)dest[t] * DIM;
    const bf16* b0 = eo + (size_t)dest[N_TOK + t] * DIM;
    int d = threadIdx.x * 4;
    bf16x4v a00 = *(const bf16x4v*)(a0 + d);
    bf16x4v a01 = *(const bf16x4v*)(a0 + off1 + d);
    bf16x4v b00 = *(const bf16x4v*)(b0 + d);
    bf16x4v b01 = *(const bf16x4v*)(b0 + off1 + d);
    float4 o;
    o.x = w0 * ((float)a00[0] + (float)a01[0]) + w1 * ((float)b00[0] + (float)b01[0]);
    o.y = w0 * ((float)a00[1] + (float)a01[1]) + w1 * ((float)b00[1] + (float)b01[1]);
    o.z = w0 * ((float)a00[2] + (float)a01[2]) + w1 * ((float)b00[2] + (float)b01[2]);
    o.w = w0 * ((float)a00[3] + (float)a01[3]) + w1 * ((float)b00[3] + (float)b01[3]);
    *(float4*)(out + (size_t)t * DIM + d) = o;
}

// ---------------------------------------------------------------------------
// Aux loss: deterministic fixed-tree reduction of probs mean + counts.
// ---------------------------------------------------------------------------
__global__ __launch_bounds__(256) void aux_kernel(const float* __restrict__ probs,
                                                  const int* __restrict__ counts,
                                                  float* __restrict__ out_aux) {
    __shared__ float sm[256][NEXP];
    float loc[NEXP];
#pragma unroll
    for (int e = 0; e < NEXP; ++e) loc[e] = 0.f;
    for (int t = threadIdx.x; t < N_TOK; t += 256)
#pragma unroll
        for (int e = 0; e < NEXP; ++e) loc[e] += probs[t * NEXP + e];
#pragma unroll
    for (int e = 0; e < NEXP; ++e) sm[threadIdx.x][e] = loc[e];
    __syncthreads();
    for (int s = 128; s > 0; s >>= 1) {
        if (threadIdx.x < s)
#pragma unroll
            for (int e = 0; e < NEXP; ++e) sm[threadIdx.x][e] += sm[threadIdx.x + s][e];
        __syncthreads();
    }
    if (threadIdx.x == 0) {
        int tot = 0;
        for (int e = 0; e < NEXP; ++e) tot += counts[e];
        float totf = tot > 0 ? (float)tot : 1.f;
        float aux = 0.f;
        for (int e = 0; e < NEXP; ++e)
            aux += ((float)counts[e] / totf) * (sm[0][e] / (float)N_TOK);
        out_aux[0] = 0.01f * (float)NEXP * aux;
    }
}

// ---------------------------------------------------------------------------
extern "C" void kernel_launch(void* const* d_in, const int* in_sizes, int n_in,
                              void* d_out, int out_size, void* d_ws, size_t ws_size,
                              hipStream_t stream) {
    const float* x  = (const float*)d_in[0];
    const float* Wr = (const float*)d_in[1];
    const float* Wg = (const float*)d_in[2];
    const float* Wu = (const float*)d_in[3];
    const float* Wd = (const float*)d_in[4];
    float* out = (float*)d_out;

    char* ws = (char*)d_ws;
    size_t off = 0;
    auto alloc = [&](size_t bytes) -> void* {
        void* p = ws + off;
        off += (bytes + 255) & ~(size_t)255;
        return p;
    };
    const size_t NW = (size_t)NEXP * FF * DIM;
    bf16*  Wg_bf = (bf16*)alloc(NW * sizeof(bf16));
    bf16*  Wu_bf = (bf16*)alloc(NW * sizeof(bf16));
    bf16*  Wd_bf = (bf16*)alloc(NW * sizeof(bf16));
    bf16*  Xe    = (bf16*)alloc((size_t)NEXP * CAP * DIM * sizeof(bf16));
    bf16*  hbuf  = (bf16*)alloc((size_t)NEXP * CAP * FF * sizeof(bf16));
    bf16*  eo    = (bf16*)alloc((size_t)2 * NEXP * CAP * DIM * sizeof(bf16));  // split-K halves
    float* probs = (float*)alloc((size_t)N_TOK * NEXP * sizeof(float));
    int*   topi  = (int*)alloc((size_t)N_TOK * 2 * sizeof(int));
    float* topw  = (float*)alloc((size_t)N_TOK * 2 * sizeof(float));
    int*   dst   = (int*)alloc((size_t)NASSIGN * sizeof(int));
    int*   accf  = (int*)alloc((size_t)NASSIGN * sizeof(int));
    int*   cnts  = (int*)alloc(NEXP * sizeof(int));

    cvt_bf16_kernel<<<2048, 256, 0, stream>>>(Wg, Wg_bf, (int)NW);
    cvt_bf16_kernel<<<2048, 256, 0, stream>>>(Wu, Wu_bf, (int)NW);
    cvt_bf16_kernel<<<2048, 256, 0, stream>>>(Wd, Wd_bf, (int)NW);
    router_kernel<<<N_TOK / 4, 256, 0, stream>>>(x, Wr, probs, topi, topw);
    rank_kernel<<<NEXP, 64, 0, stream>>>(topi, dst, accf, cnts);
    gather_kernel<<<NASSIGN, 256, 0, stream>>>(x, dst, accf, Xe);
    gateup_kernel<<<dim3(CAP / 256, FF / 128, NEXP), 512, 0, stream>>>(Xe, Wg_bf, Wu_bf, hbuf);
    down_kernel<<<dim3(CAP / 256, DIM / 256, NEXP * 2), 512, 0, stream>>>(hbuf, Wd_bf, eo);
    combine_kernel<<<N_TOK, 256, 0, stream>>>(eo, dst, accf, topw, out);
    aux_kernel<<<1, 256, 0, stream>>>(probs, cnts, out + (size_t)N_TOK * DIM);
}

// Round 6
// 896.500 us; speedup vs baseline: 1.1424x; 1.1424x over previous
//
#include <hip/hip_runtime.h>
#include <hip/hip_bf16.h>

// Problem constants (B=1)
#define N_TOK 8192
#define DIM   1024
#define NEXP  8
#define FF    4096
#define CAP   2560            // int(8192*2*1.25/8)
#define NASSIGN (N_TOK * 2)   // K=2, slot-major: j = s*N + t

typedef __bf16 bf16;
typedef __bf16 bf16x8 __attribute__((ext_vector_type(8)));
typedef __bf16 bf16x4v __attribute__((ext_vector_type(4)));
typedef float  f32x4  __attribute__((ext_vector_type(4)));

// async global->LDS DMA, 16B per lane. LDS dest = wave-uniform base + lane*16.
__device__ __forceinline__ void gl2lds16(const bf16* g, bf16* l) {
    __builtin_amdgcn_global_load_lds(
        (const __attribute__((address_space(1))) unsigned int*)g,
        (__attribute__((address_space(3))) unsigned int*)l,
        16, 0, 0);
}

// ---------------------------------------------------------------------------
// 256x256x64 GEMM core, m201-style fine-interleaved 4-phase schedule.
// 8 waves (2M x 4N), per-wave 128x64 = 8x4 frags of 16x16x32 bf16 MFMA.
// LDS: dbuf x (A 256x64 + B 256x64) = 128 KB, 1 block/CU.
// LDS groups g = 64 rows. A layout: lds row = tile row. B layout nh-major:
// r_lds = nh*128 + wn*32 + n'*16 + r16 -> dead regions are group-aligned.
// Phases (mh,nh): ph0=(0,0) ph1=(0,1) ph2=(1,0) ph3=(1,1).
// Region death: A-mh0 = groups{0,2} after ph1; B-nh0 = groups{0,1} after ph2;
// A-mh1={1,3}, B-nh1={2,3} after ph3.
// Stagger (2 gl2lds per phase, issued after the killing barrier):
//   ph0: A(kt+1) g{1,3} (other dbuf)   ph1: B(kt+1) g{2,3} (other dbuf)
//   ph2: A(kt+2) g{0,2} (just killed)  ph3: B(kt+2) g{0,1} (just killed)
// ONE vmcnt(4) per K-tile at ph3: completes all but this tile's ph2/ph3
// stages -> next K-tile provably resident after the barrier. Epilogue peel:
// tile NT-2 stages only kt+1 halves, vmcnt(0); tile NT-1 stages nothing.
// Swizzle involution: source chunk (lane&7)^(lane>>3); ds_read phys chunk
// (kk*4+c16)^(lds_row&7); lds_row&7 == lane>>3 on the staged side.
// ---------------------------------------------------------------------------
template <int NT, int AST, int BST, int BG1, int BG2>
__device__ __forceinline__ void gemm256_core(
    const bf16* __restrict__ pA, const bf16* __restrict__ pB,
    bf16* As, bf16* Bs, f32x4 acc[8][4], int wave, int lane)
{
    const int wm = wave >> 2, wn = wave & 3;
    const int r16 = lane & 15, c16 = lane >> 4;
    const int wbase = wave * 8 * 64;   // wave's slice inside a 64-row group

#define AOFF(g) ((size_t)(g) * 64 * AST)
#define BOFF(g) ((size_t)(((g) & 1) * BG1 + ((g) >> 1) * BG2) * BST)
#define SA(g, kt) gl2lds16(pA + AOFF(g) + (size_t)(kt) * 64, \
                           &As[((kt) & 1) * (256 * 64) + (g) * (64 * 64) + wbase])
#define SB(g, kt) gl2lds16(pB + BOFF(g) + (size_t)(kt) * 64, \
                           &Bs[((kt) & 1) * (256 * 64) + (g) * (64 * 64) + wbase])

    // prologue: tile0 fully + tile1 first halves, steady-state issue order
    SA(0, 0); SA(2, 0); SB(0, 0); SB(1, 0);
    SA(1, 0); SA(3, 0); SB(2, 0); SB(3, 0);
    SA(0, 1); SA(2, 1); SB(0, 1); SB(1, 1);
    asm volatile("s_waitcnt vmcnt(4)" ::: "memory");   // tile 0 resident
    __builtin_amdgcn_sched_barrier(0);
    __builtin_amdgcn_s_barrier();
    __builtin_amdgcn_sched_barrier(0);

    bf16x8 af[4][2], bfr[2][2];

#define DS_A(mh)                                                           \
    _Pragma("unroll")                                                      \
    for (int mm = 0; mm < 4; ++mm) {                                       \
        _Pragma("unroll")                                                  \
        for (int kk = 0; kk < 2; ++kk) {                                   \
            int row = wm * 128 + (mh) * 64 + mm * 16 + r16;                \
            int phys = (kk * 4 + c16) ^ (row & 7);                         \
            af[mm][kk] = *(const bf16x8*)&Asb[row * 64 + phys * 8];        \
        } }
#define DS_B(nh)                                                           \
    _Pragma("unroll")                                                      \
    for (int np = 0; np < 2; ++np) {                                       \
        _Pragma("unroll")                                                  \
        for (int kk = 0; kk < 2; ++kk) {                                   \
            int rl = (nh) * 128 + wn * 32 + np * 16 + r16;                 \
            int phys = (kk * 4 + c16) ^ (rl & 7);                          \
            bfr[np][kk] = *(const bf16x8*)&Bsb[rl * 64 + phys * 8];        \
        } }
#define PH_IN                                                              \
    __builtin_amdgcn_sched_barrier(0);                                     \
    __builtin_amdgcn_s_barrier();                                          \
    asm volatile("s_waitcnt lgkmcnt(0)" ::: "memory");                     \
    __builtin_amdgcn_sched_barrier(0);
#define MFMA16(mh, nh)                                                     \
    __builtin_amdgcn_s_setprio(1);                                         \
    _Pragma("unroll")                                                      \
    for (int mm = 0; mm < 4; ++mm)                                         \
        _Pragma("unroll")                                                  \
        for (int np = 0; np < 2; ++np)                                     \
            _Pragma("unroll")                                              \
            for (int kk = 0; kk < 2; ++kk)                                 \
                acc[(mh) * 4 + mm][(nh) * 2 + np] =                        \
                    __builtin_amdgcn_mfma_f32_16x16x32_bf16(               \
                        af[mm][kk], bfr[np][kk],                           \
                        acc[(mh) * 4 + mm][(nh) * 2 + np], 0, 0, 0);       \
    __builtin_amdgcn_s_setprio(0);
#define PH_OUT                                                             \
    __builtin_amdgcn_sched_barrier(0);                                     \
    __builtin_amdgcn_s_barrier();                                          \
    __builtin_amdgcn_sched_barrier(0);

#define TILE(kt, S1, S2, VMC) {                                            \
    const bf16* Asb = &As[((kt) & 1) * (256 * 64)];                        \
    const bf16* Bsb = &Bs[((kt) & 1) * (256 * 64)];                        \
    DS_A(0) DS_B(0)                                                        \
    if (S1) { SA(1, (kt) + 1); SA(3, (kt) + 1); }                          \
    PH_IN MFMA16(0, 0) PH_OUT                                              \
    DS_B(1)                                                                \
    if (S1) { SB(2, (kt) + 1); SB(3, (kt) + 1); }                          \
    PH_IN MFMA16(0, 1) PH_OUT                                              \
    DS_A(1) DS_B(0)                                                        \
    if (S2) { SA(0, (kt) + 2); SA(2, (kt) + 2); }                          \
    PH_IN MFMA16(1, 0) PH_OUT                                              \
    DS_B(1)                                                                \
    if (S2) { SB(0, (kt) + 2); SB(1, (kt) + 2); }                          \
    if ((VMC) == 4) { asm volatile("s_waitcnt vmcnt(4)" ::: "memory"); }   \
    else if ((VMC) == 0) { asm volatile("s_waitcnt vmcnt(0)" ::: "memory"); } \
    PH_IN MFMA16(1, 1) PH_OUT }

    for (int kt = 0; kt < NT - 2; ++kt) TILE(kt, 1, 1, 4);
    TILE(NT - 2, 1, 0, 0);
    TILE(NT - 1, 0, 0, -1);

#undef AOFF
#undef BOFF
#undef SA
#undef SB
#undef DS_A
#undef DS_B
#undef PH_IN
#undef MFMA16
#undef PH_OUT
#undef TILE
}

// ---------------------------------------------------------------------------
// fp32 -> bf16 weight conversion
// ---------------------------------------------------------------------------
__global__ __launch_bounds__(256) void cvt_bf16_kernel(const float* __restrict__ in,
                                                       bf16* __restrict__ out, int n) {
    int stride = gridDim.x * blockDim.x * 8;
    for (int i = (blockIdx.x * blockDim.x + threadIdx.x) * 8; i < n; i += stride) {
        float4 a = *(const float4*)(in + i);
        float4 b = *(const float4*)(in + i + 4);
        bf16x8 o;
        o[0] = (bf16)a.x; o[1] = (bf16)a.y; o[2] = (bf16)a.z; o[3] = (bf16)a.w;
        o[4] = (bf16)b.x; o[5] = (bf16)b.y; o[6] = (bf16)b.z; o[7] = (bf16)b.w;
        *(bf16x8*)(out + i) = o;
    }
}

// ---------------------------------------------------------------------------
// Router: logits in fp64 (top-k selection robustness), softmax, top-2.
// ---------------------------------------------------------------------------
__global__ __launch_bounds__(256) void router_kernel(const float* __restrict__ x,
                                                     const float* __restrict__ Wr,
                                                     float* __restrict__ probs,
                                                     int* __restrict__ topi,
                                                     float* __restrict__ topw) {
    int wave = threadIdx.x >> 6;
    int lane = threadIdx.x & 63;
    int t = blockIdx.x * 4 + wave;
    const float* xr = x + (size_t)t * DIM;

    double acc[NEXP];
#pragma unroll
    for (int e = 0; e < NEXP; ++e) acc[e] = 0.0;
    for (int i = lane; i < DIM; i += 64) {
        double xv = (double)xr[i];
#pragma unroll
        for (int e = 0; e < NEXP; ++e) acc[e] += xv * (double)Wr[e * DIM + i];
    }
#pragma unroll
    for (int e = 0; e < NEXP; ++e) {
        double v = acc[e];
        for (int off = 32; off > 0; off >>= 1) v += __shfl_down(v, off, 64);
        acc[e] = v;  // valid on lane 0
    }
    if (lane == 0) {
        double mx = acc[0];
        for (int e = 1; e < NEXP; ++e) if (acc[e] > mx) mx = acc[e];
        double p[NEXP], s = 0.0;
        for (int e = 0; e < NEXP; ++e) { p[e] = exp(acc[e] - mx); s += p[e]; }
        float pf[NEXP];
        for (int e = 0; e < NEXP; ++e) { pf[e] = (float)(p[e] / s); probs[t * NEXP + e] = pf[e]; }
        int e1 = 0;
        for (int e = 1; e < NEXP; ++e) if (acc[e] > acc[e1]) e1 = e;
        int e2 = -1;
        for (int e = 0; e < NEXP; ++e) {
            if (e == e1) continue;
            if (e2 < 0 || acc[e] > acc[e2]) e2 = e;
        }
        float w1 = pf[e1], w2 = pf[e2];
        float inv = 1.0f / (w1 + w2 + 1e-9f);
        topi[t * 2 + 0] = e1; topi[t * 2 + 1] = e2;
        topw[t * 2 + 0] = w1 * inv; topw[t * 2 + 1] = w2 * inv;
    }
}

// ---------------------------------------------------------------------------
// Rank/capacity in exact slot-major reference order. One wave per expert.
// ---------------------------------------------------------------------------
__global__ __launch_bounds__(64) void rank_kernel(const int* __restrict__ topi,
                                                  int* __restrict__ dest,
                                                  int* __restrict__ accf,
                                                  int* __restrict__ counts) {
    int e = blockIdx.x;
    int lane = threadIdx.x;
    const int per = NASSIGN / 64;  // 256
    int base = lane * per;
    int cnt = 0;
    for (int i = 0; i < per; ++i) {
        int j = base + i;
        int t = j & (N_TOK - 1), s = j >> 13;
        if (topi[t * 2 + s] == e) cnt++;
    }
    int sum = cnt;
    for (int off = 1; off < 64; off <<= 1) {
        int v = __shfl_up(sum, off, 64);
        if (lane >= off) sum += v;
    }
    int r = sum - cnt;                       // exclusive prefix
    int total = __shfl(sum, 63, 64);
    for (int i = 0; i < per; ++i) {
        int j = base + i;
        int t = j & (N_TOK - 1), s = j >> 13;
        if (topi[t * 2 + s] == e) {
            int acc = (r < CAP) ? 1 : 0;
            dest[j] = e * CAP + (acc ? r : 0);
            accf[j] = acc;
            r++;
        }
    }
    if (lane == 63) counts[e] = (total < CAP) ? total : CAP;
}

// ---------------------------------------------------------------------------
// Gather: x row -> bf16 capacity buffer row. One block per assignment.
// ---------------------------------------------------------------------------
__global__ __launch_bounds__(256) void gather_kernel(const float* __restrict__ x,
                                                     const int* __restrict__ dest,
                                                     const int* __restrict__ accf,
                                                     bf16* __restrict__ Xe) {
    int j = blockIdx.x;
    if (!accf[j]) return;
    int t = j & (N_TOK - 1);
    int d0 = threadIdx.x * 4;
    float4 v = *(const float4*)(x + (size_t)t * DIM + d0);
    union { bf16 h[4]; uint2 u; } tmp;
    tmp.h[0] = (bf16)v.x; tmp.h[1] = (bf16)v.y; tmp.h[2] = (bf16)v.z; tmp.h[3] = (bf16)v.w;
    *(uint2*)(Xe + (size_t)dest[j] * DIM + d0) = tmp.u;
}

// ---------------------------------------------------------------------------
// gateup: BM=256 tokens x BN=256 interleaved cols = 128 FF cols x {gate,up}.
// B lds row encodes (nh=colgrp, wn, T, r16); frag n: T=n&1, colgrp=n>>1 ->
// silu pairs (acc[cg*2], acc[cg*2+1]) are thread-local.
// Staging decomposition of l = wave*8+(lane>>3): T=(l>>4)&1, wnl=l>>5,
// r16l=l&15; col(g) = n0f + ((g&1)*2+wnl)*32 + (g>>1)*16 + r16l
// -> col(g)-col(0) = (g&1)*64 + (g>>1)*16 (lane-independent).
// ---------------------------------------------------------------------------
__global__ __launch_bounds__(512, 2) void gateup_kernel(const bf16* __restrict__ Xe,
                                                        const bf16* __restrict__ Wg,
                                                        const bf16* __restrict__ Wu,
                                                        bf16* __restrict__ hbuf) {
    const int e = blockIdx.z;
    const int m0 = blockIdx.x * 256;
    const int n0f = blockIdx.y * 128;
    const int tid = threadIdx.x, lane = tid & 63, wave = tid >> 6;
    const int wm = wave >> 2, wn = wave & 3;
    const int r16 = lane & 15, c16 = lane >> 4;

    __shared__ bf16 As[2 * 256 * 64];
    __shared__ bf16 Bs[2 * 256 * 64];

    const int l   = wave * 8 + (lane >> 3);
    const int csw = ((lane & 7) ^ (lane >> 3)) * 8;
    const bf16* pA = Xe + (size_t)e * CAP * DIM + (size_t)(m0 + l) * DIM + csw;
    const int T = (l >> 4) & 1, wnl = l >> 5, r16l = l & 15;
    const bf16* pB = (T ? Wu : Wg) + (size_t)e * FF * DIM
                   + (size_t)(n0f + wnl * 32 + r16l) * DIM + csw;

    f32x4 acc[8][4] = {};
    gemm256_core<DIM / 64, DIM, DIM, 64, 16>(pA, pB, As, Bs, acc, wave, lane);

    bf16* hp = hbuf + (size_t)e * CAP * FF;
#pragma unroll
    for (int m = 0; m < 8; ++m)
#pragma unroll
        for (int cg = 0; cg < 2; ++cg)
#pragma unroll
            for (int j = 0; j < 4; ++j) {
                float g = acc[m][cg * 2 + 0][j];
                float u = acc[m][cg * 2 + 1][j];
                float h = (g / (1.f + __expf(-g))) * u;
                int gr = m0 + wm * 128 + m * 16 + c16 * 4 + j;
                int gc = n0f + wn * 32 + cg * 16 + r16;
                hp[(size_t)gr * FF + gc] = (bf16)h;
            }
}

// ---------------------------------------------------------------------------
// down: BM=256 x BN=256 D-cols, split-K=2 (kh = blockIdx.z&1, 32 K-tiles).
// bf16 partials into eo[kh]; combine sums both halves.
// Staging: nlow=(l>>4)&1; col(g) = n0 + ((g&1)*2+wnl)*64 + (g>>1)*32 +
// nlow*16 + r16l -> col(g)-col(0) = (g&1)*128 + (g>>1)*32.
// ---------------------------------------------------------------------------
__global__ __launch_bounds__(512, 2) void down_kernel(const bf16* __restrict__ hbuf,
                                                      const bf16* __restrict__ Wd,
                                                      bf16* __restrict__ eo) {
    const int e  = blockIdx.z >> 1;
    const int kh = blockIdx.z & 1;
    const int m0 = blockIdx.x * 256;
    const int n0 = blockIdx.y * 256;
    const int tid = threadIdx.x, lane = tid & 63, wave = tid >> 6;
    const int wm = wave >> 2, wn = wave & 3;
    const int r16 = lane & 15, c16 = lane >> 4;

    __shared__ bf16 As[2 * 256 * 64];
    __shared__ bf16 Bs[2 * 256 * 64];

    const int l   = wave * 8 + (lane >> 3);
    const int csw = ((lane & 7) ^ (lane >> 3)) * 8;
    const bf16* pA = hbuf + (size_t)e * CAP * FF + (size_t)(m0 + l) * FF
                   + kh * (FF / 2) + csw;
    const int nlow = (l >> 4) & 1, wnl = l >> 5, r16l = l & 15;
    const bf16* pB = Wd + (size_t)e * DIM * FF
                   + (size_t)(n0 + wnl * 64 + nlow * 16 + r16l) * FF
                   + kh * (FF / 2) + csw;

    f32x4 acc[8][4] = {};
    gemm256_core<FF / 128, FF, FF, 128, 32>(pA, pB, As, Bs, acc, wave, lane);

    bf16* op = eo + (size_t)kh * NEXP * CAP * DIM + (size_t)e * CAP * DIM;
#pragma unroll
    for (int m = 0; m < 8; ++m)
#pragma unroll
        for (int n = 0; n < 4; ++n)
#pragma unroll
            for (int j = 0; j < 4; ++j) {
                int gr = m0 + wm * 128 + m * 16 + c16 * 4 + j;
                int gc = n0 + wn * 64 + n * 16 + r16;
                op[(size_t)gr * DIM + gc] = (bf16)acc[m][n][j];
            }
}

// ---------------------------------------------------------------------------
// Combine: out[t] = sum_s w_ts * acc_ts * (eo0[dest_ts] + eo1[dest_ts]).
// ---------------------------------------------------------------------------
__global__ __launch_bounds__(256) void combine_kernel(const bf16* __restrict__ eo,
                                                      const int* __restrict__ dest,
                                                      const int* __restrict__ accf,
                                                      const float* __restrict__ topw,
                                                      float* __restrict__ out) {
    int t = blockIdx.x;
    float w0 = accf[t] ? topw[t * 2 + 0] : 0.f;           // slot 0: j = t
    float w1 = accf[N_TOK + t] ? topw[t * 2 + 1] : 0.f;   // slot 1: j = N + t
    size_t off1 = (size_t)NEXP * CAP * DIM;
    const bf16* a0 = eo + (size_t)dest[t] * DIM;
    const bf16* b0 = eo + (size_t)dest[N_TOK + t] * DIM;
    int d = threadIdx.x * 4;
    bf16x4v a00 = *(const bf16x4v*)(a0 + d);
    bf16x4v a01 = *(const bf16x4v*)(a0 + off1 + d);
    bf16x4v b00 = *(const bf16x4v*)(b0 + d);
    bf16x4v b01 = *(const bf16x4v*)(b0 + off1 + d);
    float4 o;
    o.x = w0 * ((float)a00[0] + (float)a01[0]) + w1 * ((float)b00[0] + (float)b01[0]);
    o.y = w0 * ((float)a00[1] + (float)a01[1]) + w1 * ((float)b00[1] + (float)b01[1]);
    o.z = w0 * ((float)a00[2] + (float)a01[2]) + w1 * ((float)b00[2] + (float)b01[2]);
    o.w = w0 * ((float)a00[3] + (float)a01[3]) + w1 * ((float)b00[3] + (float)b01[3]);
    *(float4*)(out + (size_t)t * DIM + d) = o;
}

// ---------------------------------------------------------------------------
// Aux loss: deterministic fixed-tree reduction of probs mean + counts.
// ---------------------------------------------------------------------------
__global__ __launch_bounds__(256) void aux_kernel(const float* __restrict__ probs,
                                                  const int* __restrict__ counts,
                                                  float* __restrict__ out_aux) {
    __shared__ float sm[256][NEXP];
    float loc[NEXP];
#pragma unroll
    for (int e = 0; e < NEXP; ++e) loc[e] = 0.f;
    for (int t = threadIdx.x; t < N_TOK; t += 256)
#pragma unroll
        for (int e = 0; e < NEXP; ++e) loc[e] += probs[t * NEXP + e];
#pragma unroll
    for (int e = 0; e < NEXP; ++e) sm[threadIdx.x][e] = loc[e];
    __syncthreads();
    for (int s = 128; s > 0; s >>= 1) {
        if (threadIdx.x < s)
#pragma unroll
            for (int e = 0; e < NEXP; ++e) sm[threadIdx.x][e] += sm[threadIdx.x + s][e];
        __syncthreads();
    }
    if (threadIdx.x == 0) {
        int tot = 0;
        for (int e = 0; e < NEXP; ++e) tot += counts[e];
        float totf = tot > 0 ? (float)tot : 1.f;
        float aux = 0.f;
        for (int e = 0; e < NEXP; ++e)
            aux += ((float)counts[e] / totf) * (sm[0][e] / (float)N_TOK);
        out_aux[0] = 0.01f * (float)NEXP * aux;
    }
}

// ---------------------------------------------------------------------------
extern "C" void kernel_launch(void* const* d_in, const int* in_sizes, int n_in,
                              void* d_out, int out_size, void* d_ws, size_t ws_size,
                              hipStream_t stream) {
    const float* x  = (const float*)d_in[0];
    const float* Wr = (const float*)d_in[1];
    const float* Wg = (const float*)d_in[2];
    const float* Wu = (const float*)d_in[3];
    const float* Wd = (const float*)d_in[4];
    float* out = (float*)d_out;

    char* ws = (char*)d_ws;
    size_t off = 0;
    auto alloc = [&](size_t bytes) -> void* {
        void* p = ws + off;
        off += (bytes + 255) & ~(size_t)255;
        return p;
    };
    const size_t NW = (size_t)NEXP * FF * DIM;
    bf16*  Wg_bf = (bf16*)alloc(NW * sizeof(bf16));
    bf16*  Wu_bf = (bf16*)alloc(NW * sizeof(bf16));
    bf16*  Wd_bf = (bf16*)alloc(NW * sizeof(bf16));
    bf16*  Xe    = (bf16*)alloc((size_t)NEXP * CAP * DIM * sizeof(bf16));
    bf16*  hbuf  = (bf16*)alloc((size_t)NEXP * CAP * FF * sizeof(bf16));
    bf16*  eo    = (bf16*)alloc((size_t)2 * NEXP * CAP * DIM * sizeof(bf16));  // split-K halves
    float* probs = (float*)alloc((size_t)N_TOK * NEXP * sizeof(float));
    int*   topi  = (int*)alloc((size_t)N_TOK * 2 * sizeof(int));
    float* topw  = (float*)alloc((size_t)N_TOK * 2 * sizeof(float));
    int*   dst   = (int*)alloc((size_t)NASSIGN * sizeof(int));
    int*   accf  = (int*)alloc((size_t)NASSIGN * sizeof(int));
    int*   cnts  = (int*)alloc(NEXP * sizeof(int));

    cvt_bf16_kernel<<<2048, 256, 0, stream>>>(Wg, Wg_bf, (int)NW);
    cvt_bf16_kernel<<<2048, 256, 0, stream>>>(Wu, Wu_bf, (int)NW);
    cvt_bf16_kernel<<<2048, 256, 0, stream>>>(Wd, Wd_bf, (int)NW);
    router_kernel<<<N_TOK / 4, 256, 0, stream>>>(x, Wr, probs, topi, topw);
    rank_kernel<<<NEXP, 64, 0, stream>>>(topi, dst, accf, cnts);
    gather_kernel<<<NASSIGN, 256, 0, stream>>>(x, dst, accf, Xe);
    gateup_kernel<<<dim3(CAP / 256, FF / 128, NEXP), 512, 0, stream>>>(Xe, Wg_bf, Wu_bf, hbuf);
    down_kernel<<<dim3(CAP / 256, DIM / 256, NEXP * 2), 512, 0, stream>>>(hbuf, Wd_bf, eo);
    combine_kernel<<<N_TOK, 256, 0, stream>>>(eo, dst, accf, topw, out);
    aux_kernel<<<1, 256, 0, stream>>>(probs, cnts, out + (size_t)N_TOK * DIM);
}

// Round 7
// 853.019 us; speedup vs baseline: 1.2007x; 1.0510x over previous
//
#include <hip/hip_runtime.h>
#include <hip/hip_bf16.h>

// Problem constants (B=1)
#define N_TOK 8192
#define DIM   1024
#define NEXP  8
#define FF    4096
#define CAP   2560            // int(8192*2*1.25/8)
#define NASSIGN (N_TOK * 2)   // K=2, slot-major: j = s*N + t

typedef __bf16 bf16;
typedef __bf16 bf16x8 __attribute__((ext_vector_type(8)));
typedef __bf16 bf16x4v __attribute__((ext_vector_type(4)));
typedef float  f32x4  __attribute__((ext_vector_type(4)));

// async global->LDS DMA, 16B per lane. LDS dest = wave-uniform base + lane*16.
__device__ __forceinline__ void gl2lds16(const bf16* g, bf16* l) {
    __builtin_amdgcn_global_load_lds(
        (const __attribute__((address_space(1))) unsigned int*)g,
        (__attribute__((address_space(3))) unsigned int*)l,
        16, 0, 0);
}

// ---------------------------------------------------------------------------
// 256x256x64 GEMM core — catalog-minimum 2-phase schedule (T3 recipe):
//   prologue STAGE(0); vmcnt(0); barrier;
//   per K-tile: STAGE(kt+1) [other dbuf] -> ds_read B (8 b128) ->
//     per mh: ds_read A-half (8 b128), setprio(1) 32 MFMA setprio(0)
//   -> vmcnt(0) -> ONE s_barrier.
// No explicit lgkmcnt: ds_reads are compiler-visible loads on __shared__
// (declared HERE so addrspace(3) is guaranteed) -> compiler emits fine-grained
// lgkmcnt before dependent MFMAs and may overlap read-drain with MFMA.
// Hazards: STAGE(kt+1) targets buf[kt+1&1] (not read this tile). vmcnt(0)
// before the barrier -> after barrier release ALL waves' DMAs landed.
// Reads of buf[kt&1] retire before each wave's MFMAs issue -> before barrier
// arrival -> next tile's STAGE(kt+2) into buf[kt&1] cannot clobber.
// Swizzle involution: source chunk (lane&7)^(lane>>3); ds_read phys chunk
// (kk*4+c16)^(lds_row&7); lds_row&7 == lane>>3 on the staged side.
// 24 b128 reads/wave/tile (A 16 + B 8, no re-reads).
// ---------------------------------------------------------------------------
template <int NT, int AST, int BST, int BG1, int BG2>
__device__ __forceinline__ void gemm256_2ph(
    const bf16* __restrict__ pA, const bf16* __restrict__ pB,
    f32x4 acc[8][4], int wave, int lane)
{
    __shared__ bf16 As[2 * 256 * 64];
    __shared__ bf16 Bs[2 * 256 * 64];

    const int wm = wave >> 2, wn = wave & 3;
    const int r16 = lane & 15, c16 = lane >> 4;
    const int wbase = wave * 8 * 64;   // wave's 8-row slice inside a 64-row group

    auto STAGE = [&](int kt) {
        const int b = kt & 1;
        const bf16* a  = pA + (size_t)kt * 64;
        const bf16* bb = pB + (size_t)kt * 64;
#pragma unroll
        for (int g = 0; g < 4; ++g)
            gl2lds16(a + (size_t)g * 64 * AST,
                     &As[b * (256 * 64) + g * (64 * 64) + wbase]);
#pragma unroll
        for (int g = 0; g < 4; ++g)
            gl2lds16(bb + (size_t)((g & 1) * BG1 + (g >> 1) * BG2) * BST,
                     &Bs[b * (256 * 64) + g * (64 * 64) + wbase]);
    };

    STAGE(0);
    asm volatile("s_waitcnt vmcnt(0)" ::: "memory");
    __builtin_amdgcn_sched_barrier(0);
    __builtin_amdgcn_s_barrier();
    __builtin_amdgcn_sched_barrier(0);

    for (int kt = 0; kt < NT; ++kt) {
        if (kt + 1 < NT) STAGE(kt + 1);
        const bf16* Asb = &As[(kt & 1) * (256 * 64)];
        const bf16* Bsb = &Bs[(kt & 1) * (256 * 64)];

        // B fragments, both halves (8 x ds_read_b128), held for the tile
        bf16x8 bfr[4][2];
#pragma unroll
        for (int nh = 0; nh < 2; ++nh)
#pragma unroll
            for (int np = 0; np < 2; ++np)
#pragma unroll
                for (int kk = 0; kk < 2; ++kk) {
                    int rl = nh * 128 + wn * 32 + np * 16 + r16;
                    int phys = (kk * 4 + c16) ^ (rl & 7);
                    bfr[nh * 2 + np][kk] = *(const bf16x8*)&Bsb[rl * 64 + phys * 8];
                }
#pragma unroll
        for (int mh = 0; mh < 2; ++mh) {
            bf16x8 af[4][2];
#pragma unroll
            for (int mm = 0; mm < 4; ++mm)
#pragma unroll
                for (int kk = 0; kk < 2; ++kk) {
                    int row = wm * 128 + mh * 64 + mm * 16 + r16;
                    int phys = (kk * 4 + c16) ^ (row & 7);
                    af[mm][kk] = *(const bf16x8*)&Asb[row * 64 + phys * 8];
                }
            __builtin_amdgcn_s_setprio(1);
#pragma unroll
            for (int mm = 0; mm < 4; ++mm)
#pragma unroll
                for (int nf = 0; nf < 4; ++nf)
#pragma unroll
                    for (int kk = 0; kk < 2; ++kk)
                        acc[mh * 4 + mm][nf] =
                            __builtin_amdgcn_mfma_f32_16x16x32_bf16(
                                af[mm][kk], bfr[nf][kk], acc[mh * 4 + mm][nf], 0, 0, 0);
            __builtin_amdgcn_s_setprio(0);
        }

        asm volatile("s_waitcnt vmcnt(0)" ::: "memory");
        __builtin_amdgcn_sched_barrier(0);
        __builtin_amdgcn_s_barrier();
        __builtin_amdgcn_sched_barrier(0);
    }
}

// ---------------------------------------------------------------------------
// fp32 -> bf16 weight conversion
// ---------------------------------------------------------------------------
__global__ __launch_bounds__(256) void cvt_bf16_kernel(const float* __restrict__ in,
                                                       bf16* __restrict__ out, int n) {
    int stride = gridDim.x * blockDim.x * 8;
    for (int i = (blockIdx.x * blockDim.x + threadIdx.x) * 8; i < n; i += stride) {
        float4 a = *(const float4*)(in + i);
        float4 b = *(const float4*)(in + i + 4);
        bf16x8 o;
        o[0] = (bf16)a.x; o[1] = (bf16)a.y; o[2] = (bf16)a.z; o[3] = (bf16)a.w;
        o[4] = (bf16)b.x; o[5] = (bf16)b.y; o[6] = (bf16)b.z; o[7] = (bf16)b.w;
        *(bf16x8*)(out + i) = o;
    }
}

// ---------------------------------------------------------------------------
// Router: logits in fp64 (top-k selection robustness), softmax, top-2.
// ---------------------------------------------------------------------------
__global__ __launch_bounds__(256) void router_kernel(const float* __restrict__ x,
                                                     const float* __restrict__ Wr,
                                                     float* __restrict__ probs,
                                                     int* __restrict__ topi,
                                                     float* __restrict__ topw) {
    int wave = threadIdx.x >> 6;
    int lane = threadIdx.x & 63;
    int t = blockIdx.x * 4 + wave;
    const float* xr = x + (size_t)t * DIM;

    double acc[NEXP];
#pragma unroll
    for (int e = 0; e < NEXP; ++e) acc[e] = 0.0;
    for (int i = lane; i < DIM; i += 64) {
        double xv = (double)xr[i];
#pragma unroll
        for (int e = 0; e < NEXP; ++e) acc[e] += xv * (double)Wr[e * DIM + i];
    }
#pragma unroll
    for (int e = 0; e < NEXP; ++e) {
        double v = acc[e];
        for (int off = 32; off > 0; off >>= 1) v += __shfl_down(v, off, 64);
        acc[e] = v;  // valid on lane 0
    }
    if (lane == 0) {
        double mx = acc[0];
        for (int e = 1; e < NEXP; ++e) if (acc[e] > mx) mx = acc[e];
        double p[NEXP], s = 0.0;
        for (int e = 0; e < NEXP; ++e) { p[e] = exp(acc[e] - mx); s += p[e]; }
        float pf[NEXP];
        for (int e = 0; e < NEXP; ++e) { pf[e] = (float)(p[e] / s); probs[t * NEXP + e] = pf[e]; }
        int e1 = 0;
        for (int e = 1; e < NEXP; ++e) if (acc[e] > acc[e1]) e1 = e;
        int e2 = -1;
        for (int e = 0; e < NEXP; ++e) {
            if (e == e1) continue;
            if (e2 < 0 || acc[e] > acc[e2]) e2 = e;
        }
        float w1 = pf[e1], w2 = pf[e2];
        float inv = 1.0f / (w1 + w2 + 1e-9f);
        topi[t * 2 + 0] = e1; topi[t * 2 + 1] = e2;
        topw[t * 2 + 0] = w1 * inv; topw[t * 2 + 1] = w2 * inv;
    }
}

// ---------------------------------------------------------------------------
// Rank/capacity in exact slot-major reference order. One wave per expert.
// ---------------------------------------------------------------------------
__global__ __launch_bounds__(64) void rank_kernel(const int* __restrict__ topi,
                                                  int* __restrict__ dest,
                                                  int* __restrict__ accf,
                                                  int* __restrict__ counts) {
    int e = blockIdx.x;
    int lane = threadIdx.x;
    const int per = NASSIGN / 64;  // 256
    int base = lane * per;
    int cnt = 0;
    for (int i = 0; i < per; ++i) {
        int j = base + i;
        int t = j & (N_TOK - 1), s = j >> 13;
        if (topi[t * 2 + s] == e) cnt++;
    }
    int sum = cnt;
    for (int off = 1; off < 64; off <<= 1) {
        int v = __shfl_up(sum, off, 64);
        if (lane >= off) sum += v;
    }
    int r = sum - cnt;                       // exclusive prefix
    int total = __shfl(sum, 63, 64);
    for (int i = 0; i < per; ++i) {
        int j = base + i;
        int t = j & (N_TOK - 1), s = j >> 13;
        if (topi[t * 2 + s] == e) {
            int acc = (r < CAP) ? 1 : 0;
            dest[j] = e * CAP + (acc ? r : 0);
            accf[j] = acc;
            r++;
        }
    }
    if (lane == 63) counts[e] = (total < CAP) ? total : CAP;
}

// ---------------------------------------------------------------------------
// Gather: x row -> bf16 capacity buffer row. One block per assignment.
// ---------------------------------------------------------------------------
__global__ __launch_bounds__(256) void gather_kernel(const float* __restrict__ x,
                                                     const int* __restrict__ dest,
                                                     const int* __restrict__ accf,
                                                     bf16* __restrict__ Xe) {
    int j = blockIdx.x;
    if (!accf[j]) return;
    int t = j & (N_TOK - 1);
    int d0 = threadIdx.x * 4;
    float4 v = *(const float4*)(x + (size_t)t * DIM + d0);
    union { bf16 h[4]; uint2 u; } tmp;
    tmp.h[0] = (bf16)v.x; tmp.h[1] = (bf16)v.y; tmp.h[2] = (bf16)v.z; tmp.h[3] = (bf16)v.w;
    *(uint2*)(Xe + (size_t)dest[j] * DIM + d0) = tmp.u;
}

// ---------------------------------------------------------------------------
// gateup: BM=256 tokens x BN=256 interleaved cols = 128 FF cols x {gate,up}.
// Same fragment/staging math as r6 (validated). XCD remap: e = lin&7 (one
// expert per XCD under rr dispatch); within an XCD chunk x varies fastest so
// 10 co-resident blocks share each weight panel in that XCD's L2.
// ---------------------------------------------------------------------------
__global__ __launch_bounds__(512, 2) void gateup_kernel(const bf16* __restrict__ Xe,
                                                        const bf16* __restrict__ Wg,
                                                        const bf16* __restrict__ Wu,
                                                        bf16* __restrict__ hbuf) {
    const int lin = blockIdx.x + 10 * (blockIdx.y + 32 * blockIdx.z); // 0..2559
    const int e   = lin & 7;
    const int rem = lin >> 3;            // 0..319
    const int m0  = (rem % 10) * 256;
    const int n0f = (rem / 10) * 128;
    const int tid = threadIdx.x, lane = tid & 63, wave = tid >> 6;
    const int wm = wave >> 2, wn = wave & 3;
    const int r16 = lane & 15, c16 = lane >> 4;

    const int l   = wave * 8 + (lane >> 3);
    const int csw = ((lane & 7) ^ (lane >> 3)) * 8;
    const bf16* pA = Xe + (size_t)e * CAP * DIM + (size_t)(m0 + l) * DIM + csw;
    const int T = (l >> 4) & 1, wnl = l >> 5, r16l = l & 15;
    const bf16* pB = (T ? Wu : Wg) + (size_t)e * FF * DIM
                   + (size_t)(n0f + wnl * 32 + r16l) * DIM + csw;

    f32x4 acc[8][4] = {};
    gemm256_2ph<DIM / 64, DIM, DIM, 64, 16>(pA, pB, acc, wave, lane);

    bf16* hp = hbuf + (size_t)e * CAP * FF;
#pragma unroll
    for (int m = 0; m < 8; ++m)
#pragma unroll
        for (int cg = 0; cg < 2; ++cg)
#pragma unroll
            for (int j = 0; j < 4; ++j) {
                float g = acc[m][cg * 2 + 0][j];
                float u = acc[m][cg * 2 + 1][j];
                float h = (g / (1.f + __expf(-g))) * u;
                int gr = m0 + wm * 128 + m * 16 + c16 * 4 + j;
                int gc = n0f + wn * 32 + cg * 16 + r16;
                hp[(size_t)gr * FF + gc] = (bf16)h;
            }
}

// ---------------------------------------------------------------------------
// down: BM=256 x BN=256 D-cols, split-K=2. XCD remap: XCD k owns expert k
// (kh 0,1); x fastest within chunk -> weight-panel sharing in L2.
// ---------------------------------------------------------------------------
__global__ __launch_bounds__(512, 2) void down_kernel(const bf16* __restrict__ hbuf,
                                                      const bf16* __restrict__ Wd,
                                                      bf16* __restrict__ eo) {
    const int lin = blockIdx.x + 10 * (blockIdx.y + 4 * blockIdx.z); // 0..639
    const int xcd = lin & 7, pos = lin >> 3;       // pos 0..79
    const int zc  = xcd * 2 + pos / 40;            // 0..15
    const int e = zc >> 1, kh = zc & 1;
    const int rem40 = pos % 40;
    const int m0 = (rem40 % 10) * 256;
    const int n0 = (rem40 / 10) * 256;
    const int tid = threadIdx.x, lane = tid & 63, wave = tid >> 6;
    const int wm = wave >> 2, wn = wave & 3;
    const int r16 = lane & 15, c16 = lane >> 4;

    const int l   = wave * 8 + (lane >> 3);
    const int csw = ((lane & 7) ^ (lane >> 3)) * 8;
    const bf16* pA = hbuf + (size_t)e * CAP * FF + (size_t)(m0 + l) * FF
                   + kh * (FF / 2) + csw;
    const int nlow = (l >> 4) & 1, wnl = l >> 5, r16l = l & 15;
    const bf16* pB = Wd + (size_t)e * DIM * FF
                   + (size_t)(n0 + wnl * 64 + nlow * 16 + r16l) * FF
                   + kh * (FF / 2) + csw;

    f32x4 acc[8][4] = {};
    gemm256_2ph<FF / 128, FF, FF, 128, 32>(pA, pB, acc, wave, lane);

    bf16* op = eo + (size_t)kh * NEXP * CAP * DIM + (size_t)e * CAP * DIM;
#pragma unroll
    for (int m = 0; m < 8; ++m)
#pragma unroll
        for (int n = 0; n < 4; ++n)
#pragma unroll
            for (int j = 0; j < 4; ++j) {
                int gr = m0 + wm * 128 + m * 16 + c16 * 4 + j;
                int gc = n0 + wn * 64 + n * 16 + r16;
                op[(size_t)gr * DIM + gc] = (bf16)acc[m][n][j];
            }
}

// ---------------------------------------------------------------------------
// Combine: out[t] = sum_s w_ts * acc_ts * (eo0[dest_ts] + eo1[dest_ts]).
// ---------------------------------------------------------------------------
__global__ __launch_bounds__(256) void combine_kernel(const bf16* __restrict__ eo,
                                                      const int* __restrict__ dest,
                                                      const int* __restrict__ accf,
                                                      const float* __restrict__ topw,
                                                      float* __restrict__ out) {
    int t = blockIdx.x;
    float w0 = accf[t] ? topw[t * 2 + 0] : 0.f;           // slot 0: j = t
    float w1 = accf[N_TOK + t] ? topw[t * 2 + 1] : 0.f;   // slot 1: j = N + t
    size_t off1 = (size_t)NEXP * CAP * DIM;
    const bf16* a0 = eo + (size_t)dest[t] * DIM;
    const bf16* b0 = eo + (size_t)dest[N_TOK + t] * DIM;
    int d = threadIdx.x * 4;
    bf16x4v a00 = *(const bf16x4v*)(a0 + d);
    bf16x4v a01 = *(const bf16x4v*)(a0 + off1 + d);
    bf16x4v b00 = *(const bf16x4v*)(b0 + d);
    bf16x4v b01 = *(const bf16x4v*)(b0 + off1 + d);
    float4 o;
    o.x = w0 * ((float)a00[0] + (float)a01[0]) + w1 * ((float)b00[0] + (float)b01[0]);
    o.y = w0 * ((float)a00[1] + (float)a01[1]) + w1 * ((float)b00[1] + (float)b01[1]);
    o.z = w0 * ((float)a00[2] + (float)a01[2]) + w1 * ((float)b00[2] + (float)b01[2]);
    o.w = w0 * ((float)a00[3] + (float)a01[3]) + w1 * ((float)b00[3] + (float)b01[3]);
    *(float4*)(out + (size_t)t * DIM + d) = o;
}

// ---------------------------------------------------------------------------
// Aux loss: deterministic fixed-tree reduction of probs mean + counts.
// ---------------------------------------------------------------------------
__global__ __launch_bounds__(256) void aux_kernel(const float* __restrict__ probs,
                                                  const int* __restrict__ counts,
                                                  float* __restrict__ out_aux) {
    __shared__ float sm[256][NEXP];
    float loc[NEXP];
#pragma unroll
    for (int e = 0; e < NEXP; ++e) loc[e] = 0.f;
    for (int t = threadIdx.x; t < N_TOK; t += 256)
#pragma unroll
        for (int e = 0; e < NEXP; ++e) loc[e] += probs[t * NEXP + e];
#pragma unroll
    for (int e = 0; e < NEXP; ++e) sm[threadIdx.x][e] = loc[e];
    __syncthreads();
    for (int s = 128; s > 0; s >>= 1) {
        if (threadIdx.x < s)
#pragma unroll
            for (int e = 0; e < NEXP; ++e) sm[threadIdx.x][e] += sm[threadIdx.x + s][e];
        __syncthreads();
    }
    if (threadIdx.x == 0) {
        int tot = 0;
        for (int e = 0; e < NEXP; ++e) tot += counts[e];
        float totf = tot > 0 ? (float)tot : 1.f;
        float aux = 0.f;
        for (int e = 0; e < NEXP; ++e)
            aux += ((float)counts[e] / totf) * (sm[0][e] / (float)N_TOK);
        out_aux[0] = 0.01f * (float)NEXP * aux;
    }
}

// ---------------------------------------------------------------------------
extern "C" void kernel_launch(void* const* d_in, const int* in_sizes, int n_in,
                              void* d_out, int out_size, void* d_ws, size_t ws_size,
                              hipStream_t stream) {
    const float* x  = (const float*)d_in[0];
    const float* Wr = (const float*)d_in[1];
    const float* Wg = (const float*)d_in[2];
    const float* Wu = (const float*)d_in[3];
    const float* Wd = (const float*)d_in[4];
    float* out = (float*)d_out;

    char* ws = (char*)d_ws;
    size_t off = 0;
    auto alloc = [&](size_t bytes) -> void* {
        void* p = ws + off;
        off += (bytes + 255) & ~(size_t)255;
        return p;
    };
    const size_t NW = (size_t)NEXP * FF * DIM;
    bf16*  Wg_bf = (bf16*)alloc(NW * sizeof(bf16));
    bf16*  Wu_bf = (bf16*)alloc(NW * sizeof(bf16));
    bf16*  Wd_bf = (bf16*)alloc(NW * sizeof(bf16));
    bf16*  Xe    = (bf16*)alloc((size_t)NEXP * CAP * DIM * sizeof(bf16));
    bf16*  hbuf  = (bf16*)alloc((size_t)NEXP * CAP * FF * sizeof(bf16));
    bf16*  eo    = (bf16*)alloc((size_t)2 * NEXP * CAP * DIM * sizeof(bf16));  // split-K halves
    float* probs = (float*)alloc((size_t)N_TOK * NEXP * sizeof(float));
    int*   topi  = (int*)alloc((size_t)N_TOK * 2 * sizeof(int));
    float* topw  = (float*)alloc((size_t)N_TOK * 2 * sizeof(float));
    int*   dst   = (int*)alloc((size_t)NASSIGN * sizeof(int));
    int*   accf  = (int*)alloc((size_t)NASSIGN * sizeof(int));
    int*   cnts  = (int*)alloc(NEXP * sizeof(int));

    cvt_bf16_kernel<<<2048, 256, 0, stream>>>(Wg, Wg_bf, (int)NW);
    cvt_bf16_kernel<<<2048, 256, 0, stream>>>(Wu, Wu_bf, (int)NW);
    cvt_bf16_kernel<<<2048, 256, 0, stream>>>(Wd, Wd_bf, (int)NW);
    router_kernel<<<N_TOK / 4, 256, 0, stream>>>(x, Wr, probs, topi, topw);
    rank_kernel<<<NEXP, 64, 0, stream>>>(topi, dst, accf, cnts);
    gather_kernel<<<NASSIGN, 256, 0, stream>>>(x, dst, accf, Xe);
    gateup_kernel<<<dim3(CAP / 256, FF / 128, NEXP), 512, 0, stream>>>(Xe, Wg_bf, Wu_bf, hbuf);
    down_kernel<<<dim3(CAP / 256, DIM / 256, NEXP * 2), 512, 0, stream>>>(hbuf, Wd_bf, eo);
    combine_kernel<<<N_TOK, 256, 0, stream>>>(eo, dst, accf, topw, out);
    aux_kernel<<<1, 256, 0, stream>>>(probs, cnts, out + (size_t)N_TOK * DIM);
}

// Round 8
// 830.394 us; speedup vs baseline: 1.2334x; 1.0272x over previous
//
#include <hip/hip_runtime.h>
#include <hip/hip_bf16.h>

// Problem constants (B=1)
#define N_TOK 8192
#define DIM   1024
#define NEXP  8
#define FF    4096
#define CAP   2560            // int(8192*2*1.25/8)
#define NASSIGN (N_TOK * 2)   // K=2, slot-major: j = s*N + t
#define EOSL  ((size_t)NEXP * CAP * DIM)   // one split-K eo slice (elems)

typedef __bf16 bf16;
typedef __bf16 bf16x8 __attribute__((ext_vector_type(8)));
typedef __bf16 bf16x4v __attribute__((ext_vector_type(4)));
typedef float  f32x4  __attribute__((ext_vector_type(4)));

// async global->LDS DMA, 16B per lane. LDS dest = wave-uniform base + lane*16.
__device__ __forceinline__ void gl2lds16(const bf16* g, bf16* l) {
    __builtin_amdgcn_global_load_lds(
        (const __attribute__((address_space(1))) unsigned int*)g,
        (__attribute__((address_space(3))) unsigned int*)l,
        16, 0, 0);
}

// ---------------------------------------------------------------------------
// PERSISTENT 256x256x64 GEMM core (2ph schedule, r7-validated inner tile).
// One block per CU runs `nunits` units through a single warm pipeline:
// tile stream is flat; at a unit's last tile we stage the NEXT unit's tile 0
// (buf parity works out: NT even -> cross-unit stage lands in buf0, which the
// next unit's kt=0 reads). Only ONE cold prologue per block.
// Per tile: STAGE(next tile, other buf) -> ds_read B(8)+A(2x8) -> setprio'd
// MFMA clusters -> vmcnt(0) -> ONE s_barrier. Hazards as r7 (validated):
// reads of buf[kt&1] retire before each wave's barrier arrival; the staged
// buffer is never the one being read; epilogue touches no LDS so it needs no
// extra barrier (cross-unit staged data was drained at the prior barrier).
// Swizzle involution: source chunk (lane&7)^(lane>>3); read phys chunk
// (kk*4+c16)^(lds_row&7); lds_row&7 == lane>>3 on the staged side.
// ---------------------------------------------------------------------------
template <int NT, int AST, int BST, int BG1, int BG2, class UnitFn, class EpiFn>
__device__ __forceinline__ void gemm256_persist(
    int nunits, UnitFn unit, EpiFn epi, int wave, int lane)
{
    __shared__ bf16 As[2 * 256 * 64];
    __shared__ bf16 Bs[2 * 256 * 64];

    const int wm = wave >> 2, wn = wave & 3;
    const int r16 = lane & 15, c16 = lane >> 4;
    const int wbase = wave * 8 * 64;   // wave's 8-row slice inside a 64-row group

    auto STAGE = [&](const bf16* a, const bf16* bb, int buf) {
#pragma unroll
        for (int g = 0; g < 4; ++g)
            gl2lds16(a + (size_t)g * 64 * AST,
                     &As[buf * (256 * 64) + g * (64 * 64) + wbase]);
#pragma unroll
        for (int g = 0; g < 4; ++g)
            gl2lds16(bb + (size_t)((g & 1) * BG1 + (g >> 1) * BG2) * BST,
                     &Bs[buf * (256 * 64) + g * (64 * 64) + wbase]);
    };

    const bf16 *pA, *pB;
    unit(0, pA, pB);
    STAGE(pA, pB, 0);
    asm volatile("s_waitcnt vmcnt(0)" ::: "memory");
    __builtin_amdgcn_sched_barrier(0);
    __builtin_amdgcn_s_barrier();
    __builtin_amdgcn_sched_barrier(0);

    for (int u = 0; u < nunits; ++u) {
        const bf16 *pAn = pA, *pBn = pB;
        const bool more = (u + 1 < nunits);
        if (more) unit(u + 1, pAn, pBn);

        f32x4 acc[8][4] = {};
        for (int kt = 0; kt < NT; ++kt) {
            if (kt + 1 < NT)
                STAGE(pA + (size_t)(kt + 1) * 64, pB + (size_t)(kt + 1) * 64, (kt + 1) & 1);
            else if (more)
                STAGE(pAn, pBn, 0);   // NT even -> buf0 = next unit's kt=0 buffer

            const bf16* Asb = &As[(kt & 1) * (256 * 64)];
            const bf16* Bsb = &Bs[(kt & 1) * (256 * 64)];

            bf16x8 bfr[4][2];
#pragma unroll
            for (int nh = 0; nh < 2; ++nh)
#pragma unroll
                for (int np = 0; np < 2; ++np)
#pragma unroll
                    for (int kk = 0; kk < 2; ++kk) {
                        int rl = nh * 128 + wn * 32 + np * 16 + r16;
                        int phys = (kk * 4 + c16) ^ (rl & 7);
                        bfr[nh * 2 + np][kk] = *(const bf16x8*)&Bsb[rl * 64 + phys * 8];
                    }
#pragma unroll
            for (int mh = 0; mh < 2; ++mh) {
                bf16x8 af[4][2];
#pragma unroll
                for (int mm = 0; mm < 4; ++mm)
#pragma unroll
                    for (int kk = 0; kk < 2; ++kk) {
                        int row = wm * 128 + mh * 64 + mm * 16 + r16;
                        int phys = (kk * 4 + c16) ^ (row & 7);
                        af[mm][kk] = *(const bf16x8*)&Asb[row * 64 + phys * 8];
                    }
                __builtin_amdgcn_s_setprio(1);
#pragma unroll
                for (int mm = 0; mm < 4; ++mm)
#pragma unroll
                    for (int nf = 0; nf < 4; ++nf)
#pragma unroll
                        for (int kk = 0; kk < 2; ++kk)
                            acc[mh * 4 + mm][nf] =
                                __builtin_amdgcn_mfma_f32_16x16x32_bf16(
                                    af[mm][kk], bfr[nf][kk], acc[mh * 4 + mm][nf], 0, 0, 0);
                __builtin_amdgcn_s_setprio(0);
            }

            asm volatile("s_waitcnt vmcnt(0)" ::: "memory");
            __builtin_amdgcn_sched_barrier(0);
            __builtin_amdgcn_s_barrier();
            __builtin_amdgcn_sched_barrier(0);
        }
        epi(u, acc);
        pA = pAn; pB = pBn;
    }
}

// ---------------------------------------------------------------------------
// fp32 -> bf16 weight conversion
// ---------------------------------------------------------------------------
__global__ __launch_bounds__(256) void cvt_bf16_kernel(const float* __restrict__ in,
                                                       bf16* __restrict__ out, int n) {
    int stride = gridDim.x * blockDim.x * 8;
    for (int i = (blockIdx.x * blockDim.x + threadIdx.x) * 8; i < n; i += stride) {
        float4 a = *(const float4*)(in + i);
        float4 b = *(const float4*)(in + i + 4);
        bf16x8 o;
        o[0] = (bf16)a.x; o[1] = (bf16)a.y; o[2] = (bf16)a.z; o[3] = (bf16)a.w;
        o[4] = (bf16)b.x; o[5] = (bf16)b.y; o[6] = (bf16)b.z; o[7] = (bf16)b.w;
        *(bf16x8*)(out + i) = o;
    }
}

// ---------------------------------------------------------------------------
// Router: logits in fp64 (top-k selection robustness), softmax, top-2.
// ---------------------------------------------------------------------------
__global__ __launch_bounds__(256) void router_kernel(const float* __restrict__ x,
                                                     const float* __restrict__ Wr,
                                                     float* __restrict__ probs,
                                                     int* __restrict__ topi,
                                                     float* __restrict__ topw) {
    int wave = threadIdx.x >> 6;
    int lane = threadIdx.x & 63;
    int t = blockIdx.x * 4 + wave;
    const float* xr = x + (size_t)t * DIM;

    double acc[NEXP];
#pragma unroll
    for (int e = 0; e < NEXP; ++e) acc[e] = 0.0;
    for (int i = lane; i < DIM; i += 64) {
        double xv = (double)xr[i];
#pragma unroll
        for (int e = 0; e < NEXP; ++e) acc[e] += xv * (double)Wr[e * DIM + i];
    }
#pragma unroll
    for (int e = 0; e < NEXP; ++e) {
        double v = acc[e];
        for (int off = 32; off > 0; off >>= 1) v += __shfl_down(v, off, 64);
        acc[e] = v;  // valid on lane 0
    }
    if (lane == 0) {
        double mx = acc[0];
        for (int e = 1; e < NEXP; ++e) if (acc[e] > mx) mx = acc[e];
        double p[NEXP], s = 0.0;
        for (int e = 0; e < NEXP; ++e) { p[e] = exp(acc[e] - mx); s += p[e]; }
        float pf[NEXP];
        for (int e = 0; e < NEXP; ++e) { pf[e] = (float)(p[e] / s); probs[t * NEXP + e] = pf[e]; }
        int e1 = 0;
        for (int e = 1; e < NEXP; ++e) if (acc[e] > acc[e1]) e1 = e;
        int e2 = -1;
        for (int e = 0; e < NEXP; ++e) {
            if (e == e1) continue;
            if (e2 < 0 || acc[e] > acc[e2]) e2 = e;
        }
        float w1 = pf[e1], w2 = pf[e2];
        float inv = 1.0f / (w1 + w2 + 1e-9f);
        topi[t * 2 + 0] = e1; topi[t * 2 + 1] = e2;
        topw[t * 2 + 0] = w1 * inv; topw[t * 2 + 1] = w2 * inv;
    }
}

// ---------------------------------------------------------------------------
// Rank/capacity in exact slot-major reference order. One wave per expert.
// ---------------------------------------------------------------------------
__global__ __launch_bounds__(64) void rank_kernel(const int* __restrict__ topi,
                                                  int* __restrict__ dest,
                                                  int* __restrict__ accf,
                                                  int* __restrict__ counts) {
    int e = blockIdx.x;
    int lane = threadIdx.x;
    const int per = NASSIGN / 64;  // 256
    int base = lane * per;
    int cnt = 0;
    for (int i = 0; i < per; ++i) {
        int j = base + i;
        int t = j & (N_TOK - 1), s = j >> 13;
        if (topi[t * 2 + s] == e) cnt++;
    }
    int sum = cnt;
    for (int off = 1; off < 64; off <<= 1) {
        int v = __shfl_up(sum, off, 64);
        if (lane >= off) sum += v;
    }
    int r = sum - cnt;                       // exclusive prefix
    int total = __shfl(sum, 63, 64);
    for (int i = 0; i < per; ++i) {
        int j = base + i;
        int t = j & (N_TOK - 1), s = j >> 13;
        if (topi[t * 2 + s] == e) {
            int acc = (r < CAP) ? 1 : 0;
            dest[j] = e * CAP + (acc ? r : 0);
            accf[j] = acc;
            r++;
        }
    }
    if (lane == 63) counts[e] = (total < CAP) ? total : CAP;
}

// ---------------------------------------------------------------------------
// Gather: x row -> bf16 capacity buffer row. One block per assignment.
// ---------------------------------------------------------------------------
__global__ __launch_bounds__(256) void gather_kernel(const float* __restrict__ x,
                                                     const int* __restrict__ dest,
                                                     const int* __restrict__ accf,
                                                     bf16* __restrict__ Xe) {
    int j = blockIdx.x;
    if (!accf[j]) return;
    int t = j & (N_TOK - 1);
    int d0 = threadIdx.x * 4;
    float4 v = *(const float4*)(x + (size_t)t * DIM + d0);
    union { bf16 h[4]; uint2 u; } tmp;
    tmp.h[0] = (bf16)v.x; tmp.h[1] = (bf16)v.y; tmp.h[2] = (bf16)v.z; tmp.h[3] = (bf16)v.w;
    *(uint2*)(Xe + (size_t)dest[j] * DIM + d0) = tmp.u;
}

// ---------------------------------------------------------------------------
// gateup (persistent): grid 256, block b -> expert e=b&7 (XCD-affine under rr
// dispatch), r=b>>3 in [0,32). Unit u in [0,10): g=u*32+r in [0,320) ->
// n-tile = g/10, m-tile = g%10 (bijective). At any u-step the 32 blocks of an
// XCD span ~4 weight n-panels (~2MB, L2-fits) and share m-panels of Xe.
// BN=256 interleaved cols = 128 FF cols x {gate,up}: B col decomposition as
// r6/r7 (validated): T=(l>>4)&1 picks tensor, col = n0f + wnl*32 + r16l
// + (g&1)*64 + (g>>1)*16.
// ---------------------------------------------------------------------------
__global__ __launch_bounds__(512, 2) void gateup_kernel(const bf16* __restrict__ Xe,
                                                        const bf16* __restrict__ Wg,
                                                        const bf16* __restrict__ Wu,
                                                        bf16* __restrict__ hbuf) {
    const int b = blockIdx.x;
    const int e = b & 7, r = b >> 3;
    const int tid = threadIdx.x, lane = tid & 63, wave = tid >> 6;
    const int wm = wave >> 2, wn = wave & 3;
    const int r16 = lane & 15, c16 = lane >> 4;

    const int l   = wave * 8 + (lane >> 3);
    const int csw = ((lane & 7) ^ (lane >> 3)) * 8;
    const int T = (l >> 4) & 1, wnl = l >> 5, r16l = l & 15;
    const bf16* XeE = Xe + (size_t)e * CAP * DIM + (size_t)l * DIM + csw;
    const bf16* WE  = (T ? Wu : Wg) + (size_t)e * FF * DIM
                    + (size_t)(wnl * 32 + r16l) * DIM + csw;
    bf16* hp = hbuf + (size_t)e * CAP * FF;

    auto unit = [&](int u, const bf16*& pA, const bf16*& pB) {
        int g = u * 32 + r;
        int m = g % 10, n = g / 10;
        pA = XeE + (size_t)(m * 256) * DIM;
        pB = WE + (size_t)(n * 128) * DIM;
    };
    auto epi = [&](int u, f32x4 (&acc)[8][4]) {
        int g = u * 32 + r;
        int m0 = (g % 10) * 256, n0f = (g / 10) * 128;
#pragma unroll
        for (int m = 0; m < 8; ++m)
#pragma unroll
            for (int cg = 0; cg < 2; ++cg)
#pragma unroll
                for (int j = 0; j < 4; ++j) {
                    float gg = acc[m][cg * 2 + 0][j];
                    float uu = acc[m][cg * 2 + 1][j];
                    float h = (gg / (1.f + __expf(-gg))) * uu;
                    int gr = m0 + wm * 128 + m * 16 + c16 * 4 + j;
                    int gc = n0f + wn * 32 + cg * 16 + r16;
                    hp[(size_t)gr * FF + gc] = (bf16)h;
                }
    };
    gemm256_persist<DIM / 64, DIM, DIM, 64, 16>(10, unit, epi, wave, lane);
}

// ---------------------------------------------------------------------------
// down (persistent): grid 256, e=b&7, r=b>>3. split-K=4: unit u in [0,5):
// g=u*32+r in [0,160) -> pn=g/10 (kh=pn>>2, n-tile=pn&3), m-tile=g%10.
// Exactly 5 units/block -> no tail. bf16 partials into eo slice kh.
// B col decomposition as r7 (validated): col = n*256 + wnl*64 + nlow*16 +
// r16l + (g&1)*128 + (g>>1)*32.
// ---------------------------------------------------------------------------
__global__ __launch_bounds__(512, 2) void down_kernel(const bf16* __restrict__ hbuf,
                                                      const bf16* __restrict__ Wd,
                                                      bf16* __restrict__ eo) {
    const int b = blockIdx.x;
    const int e = b & 7, r = b >> 3;
    const int tid = threadIdx.x, lane = tid & 63, wave = tid >> 6;
    const int wm = wave >> 2, wn = wave & 3;
    const int r16 = lane & 15, c16 = lane >> 4;

    const int l   = wave * 8 + (lane >> 3);
    const int csw = ((lane & 7) ^ (lane >> 3)) * 8;
    const int nlow = (l >> 4) & 1, wnl = l >> 5, r16l = l & 15;
    const bf16* hb  = hbuf + (size_t)e * CAP * FF + (size_t)l * FF + csw;
    const bf16* WdE = Wd + (size_t)e * DIM * FF
                    + (size_t)(wnl * 64 + nlow * 16 + r16l) * FF + csw;
    bf16* eoE = eo + (size_t)e * CAP * DIM;

    auto unit = [&](int u, const bf16*& pA, const bf16*& pB) {
        int g = u * 32 + r;
        int m = g % 10, pn = g / 10;
        int kh = pn >> 2, n = pn & 3;
        pA = hb + (size_t)(m * 256) * FF + kh * (FF / 4);
        pB = WdE + (size_t)(n * 256) * FF + kh * (FF / 4);
    };
    auto epi = [&](int u, f32x4 (&acc)[8][4]) {
        int g = u * 32 + r;
        int m0 = (g % 10) * 256, pn = g / 10;
        int kh = pn >> 2, n0 = (pn & 3) * 256;
        bf16* op = eoE + (size_t)kh * EOSL;
#pragma unroll
        for (int m = 0; m < 8; ++m)
#pragma unroll
            for (int nf = 0; nf < 4; ++nf)
#pragma unroll
                for (int j = 0; j < 4; ++j) {
                    int gr = m0 + wm * 128 + m * 16 + c16 * 4 + j;
                    int gc = n0 + wn * 64 + nf * 16 + r16;
                    op[(size_t)gr * DIM + gc] = (bf16)acc[m][nf][j];
                }
    };
    gemm256_persist<(FF / 4) / 64, FF, FF, 128, 32>(5, unit, epi, wave, lane);
}

// ---------------------------------------------------------------------------
// Combine: out[t] = sum_s w_ts * acc_ts * sum_{kh<4} eo[kh][dest_ts].
// ---------------------------------------------------------------------------
__global__ __launch_bounds__(256) void combine_kernel(const bf16* __restrict__ eo,
                                                      const int* __restrict__ dest,
                                                      const int* __restrict__ accf,
                                                      const float* __restrict__ topw,
                                                      float* __restrict__ out) {
    int t = blockIdx.x;
    float w0 = accf[t] ? topw[t * 2 + 0] : 0.f;           // slot 0: j = t
    float w1 = accf[N_TOK + t] ? topw[t * 2 + 1] : 0.f;   // slot 1: j = N + t
    const bf16* a0 = eo + (size_t)dest[t] * DIM;
    const bf16* b0 = eo + (size_t)dest[N_TOK + t] * DIM;
    int d = threadIdx.x * 4;
    float ax = 0, ay = 0, az = 0, aw = 0, bx = 0, by = 0, bz = 0, bw = 0;
#pragma unroll
    for (int s4 = 0; s4 < 4; ++s4) {
        bf16x4v a = *(const bf16x4v*)(a0 + (size_t)s4 * EOSL + d);
        bf16x4v bb = *(const bf16x4v*)(b0 + (size_t)s4 * EOSL + d);
        ax += (float)a[0]; ay += (float)a[1]; az += (float)a[2]; aw += (float)a[3];
        bx += (float)bb[0]; by += (float)bb[1]; bz += (float)bb[2]; bw += (float)bb[3];
    }
    float4 o;
    o.x = w0 * ax + w1 * bx;
    o.y = w0 * ay + w1 * by;
    o.z = w0 * az + w1 * bz;
    o.w = w0 * aw + w1 * bw;
    *(float4*)(out + (size_t)t * DIM + d) = o;
}

// ---------------------------------------------------------------------------
// Aux loss: deterministic fixed-tree reduction of probs mean + counts.
// ---------------------------------------------------------------------------
__global__ __launch_bounds__(256) void aux_kernel(const float* __restrict__ probs,
                                                  const int* __restrict__ counts,
                                                  float* __restrict__ out_aux) {
    __shared__ float sm[256][NEXP];
    float loc[NEXP];
#pragma unroll
    for (int e = 0; e < NEXP; ++e) loc[e] = 0.f;
    for (int t = threadIdx.x; t < N_TOK; t += 256)
#pragma unroll
        for (int e = 0; e < NEXP; ++e) loc[e] += probs[t * NEXP + e];
#pragma unroll
    for (int e = 0; e < NEXP; ++e) sm[threadIdx.x][e] = loc[e];
    __syncthreads();
    for (int s = 128; s > 0; s >>= 1) {
        if (threadIdx.x < s)
#pragma unroll
            for (int e = 0; e < NEXP; ++e) sm[threadIdx.x][e] += sm[threadIdx.x + s][e];
        __syncthreads();
    }
    if (threadIdx.x == 0) {
        int tot = 0;
        for (int e = 0; e < NEXP; ++e) tot += counts[e];
        float totf = tot > 0 ? (float)tot : 1.f;
        float aux = 0.f;
        for (int e = 0; e < NEXP; ++e)
            aux += ((float)counts[e] / totf) * (sm[0][e] / (float)N_TOK);
        out_aux[0] = 0.01f * (float)NEXP * aux;
    }
}

// ---------------------------------------------------------------------------
extern "C" void kernel_launch(void* const* d_in, const int* in_sizes, int n_in,
                              void* d_out, int out_size, void* d_ws, size_t ws_size,
                              hipStream_t stream) {
    const float* x  = (const float*)d_in[0];
    const float* Wr = (const float*)d_in[1];
    const float* Wg = (const float*)d_in[2];
    const float* Wu = (const float*)d_in[3];
    const float* Wd = (const float*)d_in[4];
    float* out = (float*)d_out;

    char* ws = (char*)d_ws;
    size_t off = 0;
    auto alloc = [&](size_t bytes) -> void* {
        void* p = ws + off;
        off += (bytes + 255) & ~(size_t)255;
        return p;
    };
    const size_t NW = (size_t)NEXP * FF * DIM;
    // Layout: Wd_bf FIRST so eo (4 bf16 split-K slices, 167.8 MB) can alias
    // Wg_bf+Wu_bf+Xe (176.2 MB) -- all three are dead once gateup completes,
    // and cvt/gather rewrite them on every call (replay-safe).
    bf16*  Wd_bf = (bf16*)alloc(NW * sizeof(bf16));
    bf16*  Wg_bf = (bf16*)alloc(NW * sizeof(bf16));
    bf16*  Wu_bf = (bf16*)alloc(NW * sizeof(bf16));
    bf16*  Xe    = (bf16*)alloc((size_t)NEXP * CAP * DIM * sizeof(bf16));
    bf16*  hbuf  = (bf16*)alloc((size_t)NEXP * CAP * FF * sizeof(bf16));
    float* probs = (float*)alloc((size_t)N_TOK * NEXP * sizeof(float));
    int*   topi  = (int*)alloc((size_t)N_TOK * 2 * sizeof(int));
    float* topw  = (float*)alloc((size_t)N_TOK * 2 * sizeof(float));
    int*   dst   = (int*)alloc((size_t)NASSIGN * sizeof(int));
    int*   accf  = (int*)alloc((size_t)NASSIGN * sizeof(int));
    int*   cnts  = (int*)alloc(NEXP * sizeof(int));
    bf16*  eo    = Wg_bf;   // alias (see above): 4*EOSL*2B <= Wg+Wu+Xe bytes

    cvt_bf16_kernel<<<2048, 256, 0, stream>>>(Wg, Wg_bf, (int)NW);
    cvt_bf16_kernel<<<2048, 256, 0, stream>>>(Wu, Wu_bf, (int)NW);
    cvt_bf16_kernel<<<2048, 256, 0, stream>>>(Wd, Wd_bf, (int)NW);
    router_kernel<<<N_TOK / 4, 256, 0, stream>>>(x, Wr, probs, topi, topw);
    rank_kernel<<<NEXP, 64, 0, stream>>>(topi, dst, accf, cnts);
    gather_kernel<<<NASSIGN, 256, 0, stream>>>(x, dst, accf, Xe);
    gateup_kernel<<<256, 512, 0, stream>>>(Xe, Wg_bf, Wu_bf, hbuf);
    down_kernel<<<256, 512, 0, stream>>>(hbuf, Wd_bf, eo);
    combine_kernel<<<N_TOK, 256, 0, stream>>>(eo, dst, accf, topw, out);
    aux_kernel<<<1, 256, 0, stream>>>(probs, cnts, out + (size_t)N_TOK * DIM);
}